// Round 1
// 698.805 us; speedup vs baseline: 1.3603x; 1.3603x over previous
//
#include <hip/hip_runtime.h>
#include <cstdint>
#include <cstddef>

#define B_ 2048
#define N_ 62
#define FIN_ 128
#define HID_ 512
#define HEADS_ 8
#define FOUT_ 64
#define LAYERS_ 3
#define M_ (B_*N_)

typedef __bf16 bf16x8 __attribute__((ext_vector_type(8)));
typedef float  f32x4  __attribute__((ext_vector_type(4)));
typedef unsigned short u16;

static __device__ __forceinline__ u16 f2bf(float f) {
    union { float f; uint32_t u; } v; v.f = f;
    uint32_t u = v.u;
    return (u16)((u + 0x7fffu + ((u >> 16) & 1u)) >> 16);
}
static __device__ __forceinline__ float bf2f(u16 s) {
    union { uint32_t u; float f; } v; v.u = ((uint32_t)s) << 16;
    return v.f;
}
static __device__ __forceinline__ float rdlane(float v, int l) {
    union { float f; int i; } a, b; a.f = v;
    b.i = __builtin_amdgcn_readlane(a.i, l);
    return b.f;
}

// ---------------------------------------------------------------------------
// Pack transposed bf16 weights: wmlp_t[n][k]; wgat_t[l][n][k] (n = head*64+d)
// ---------------------------------------------------------------------------
__global__ __launch_bounds__(256) void repack_w(
    const float* __restrict__ Wm, const float* __restrict__ Wg,
    u16* __restrict__ wmlp_t, u16* __restrict__ wgat_t)
{
    int idx = blockIdx.x * 256 + threadIdx.x;
    const int T1 = HID_ * FIN_;
    const int T2 = LAYERS_ * HID_ * HID_;
    if (idx < T1) {
        int n = idx / FIN_, k = idx % FIN_;
        wmlp_t[idx] = f2bf(Wm[k * HID_ + n]);
    } else if (idx < T1 + T2) {
        int j = idx - T1;
        int l = j / (HID_ * HID_);
        int r = j % (HID_ * HID_);
        int n = r / HID_, k = r % HID_;
        wgat_t[j] = f2bf(Wg[(((size_t)(l * HEADS_ + (n >> 6))) * HID_ + k) * FOUT_ + (n & 63)]);
    }
}

// ---------------------------------------------------------------------------
// adjacency -> per-row 64-bit masks + transposed (per-column) masks
// ---------------------------------------------------------------------------
__global__ __launch_bounds__(256) void build_masks(
    const int* __restrict__ adj, uint64_t* __restrict__ masks,
    uint64_t* __restrict__ masksT)
{
    __shared__ uint32_t m32[128];
    const int b = blockIdx.x, tid = threadIdx.x;
    if (tid < 128) m32[tid] = 0;
    __syncthreads();
    const int* a = adj + (size_t)b * N_ * N_;
    for (int idx = tid; idx < N_ * N_; idx += 256) {
        int i = idx / N_, j = idx % N_;
        if (a[idx] > 0) atomicOr(&m32[i * 2 + (j >> 5)], 1u << (j & 31));
    }
    __syncthreads();
    if (tid < 128) ((uint32_t*)(masks + (size_t)b * 64))[tid] = m32[tid];
    if (tid < 64) {
        int j = tid;
        uint64_t c = 0;
        for (int i = 0; i < N_; i++) {
            uint64_t bit = (m32[i * 2 + (j >> 5)] >> (j & 31)) & 1u;
            c |= bit << i;
        }
        masksT[(size_t)b * 64 + j] = c;
    }
}

// ---------------------------------------------------------------------------
// Fully fused network: BN -> MLP -> 3x GAT -> pool -> logits, one block/graph.
// LDS: buf (73728 B) aliased as {x-stage | hin[64][520] | hT[512][72]},
//      msk (512 B), fstat F1/LS (4 KB + lg). Total 78368 B -> 2 blocks/CU.
// Waves = heads. f1/f2 -> stats -> PV is wave-local (no barriers).
// ---------------------------------------------------------------------------
#define S_IN 520     // u16 stride hin/hout [64][S_IN]
#define S_T  72      // u16 stride hT [512][S_T]
#define S_X  136     // u16 stride x-stage [64][S_X]
#define X0   28160   // u16 offset of x-stage region inside buf

__global__ __launch_bounds__(512, 4) void gat_fused(
    const float* __restrict__ x,
    const float* __restrict__ bng, const float* __restrict__ bnb,
    const float* __restrict__ bnm, const float* __restrict__ bnv,
    const u16* __restrict__ wmlp_t, const float* __restrict__ bm,
    const u16* __restrict__ wgat_t, const float* __restrict__ ag,
    const uint64_t* __restrict__ masks, const uint64_t* __restrict__ masksT,
    const float* __restrict__ Wout, const float* __restrict__ bout,
    float* __restrict__ out)
{
    __shared__ __align__(16) u16 buf[36864];
    __shared__ uint64_t msk[64];
    __shared__ __align__(16) float fstat[1032];
    float* F1 = fstat;          // [8][64] f1 per (head, j)
    float* LS = fstat + 512;    // [8][64] m + ln(s) per (head, j)

    const int tid = threadIdx.x, b = blockIdx.x;
    const int wave = tid >> 6, lane = tid & 63;
    const int lr = lane & 15, lq = lane >> 4;
    const int w64 = wave * 64;

    // per-lane transposed column mask (bit i = adj[i][lane])
    const uint64_t cm = masksT[(size_t)b * 64 + lane];
    const uint32_t cml = (uint32_t)cm, cmh = (uint32_t)(cm >> 32);

    // ---- stage BN(x) -> xs bf16 [64][136] (rows 62,63 zero); stage msk ----
    {
        const float* xg = x + (size_t)b * N_ * FIN_;
        for (int idx = tid; idx < 2048; idx += 512) {
            int n = idx >> 5, kq = idx & 31;
            ushort4 o = {0, 0, 0, 0};
            if (n < N_) {
                float s = bng[n] * rsqrtf(bnv[n] + 1e-5f);
                float sh = bnb[n] - bnm[n] * s;
                float4 v = *(const float4*)(xg + n * FIN_ + kq * 4);
                o.x = f2bf(v.x * s + sh); o.y = f2bf(v.y * s + sh);
                o.z = f2bf(v.z * s + sh); o.w = f2bf(v.w * s + sh);
            }
            *(ushort4*)&buf[X0 + n * S_X + kq * 4] = o;
        }
        if (tid < 64) msk[tid] = (tid < N_) ? masks[(size_t)b * 64 + tid] : 0ull;
    }
    __syncthreads();

    // ---- MLP: hin = xs @ Wmlp + bias (each wave computes 64 cols) ----
    {
        f32x4 acc[4][4];
#pragma unroll
        for (int mt = 0; mt < 4; mt++)
#pragma unroll
            for (int nt = 0; nt < 4; nt++) acc[mt][nt] = (f32x4){0.f, 0.f, 0.f, 0.f};
        const int c0 = w64;
#pragma unroll
        for (int kt = 0; kt < 4; kt++) {
            int k0 = kt * 32;
            bf16x8 af[4];
#pragma unroll
            for (int mt = 0; mt < 4; mt++)
                af[mt] = *(const bf16x8*)&buf[X0 + (mt * 16 + lr) * S_X + k0 + lq * 8];
#pragma unroll
            for (int nt = 0; nt < 4; nt++) {
                bf16x8 bfr = *(const bf16x8*)(wmlp_t + (size_t)(c0 + nt * 16 + lr) * FIN_ + k0 + lq * 8);
#pragma unroll
                for (int mt = 0; mt < 4; mt++)
                    acc[mt][nt] = __builtin_amdgcn_mfma_f32_16x16x32_bf16(
                        af[mt], bfr, acc[mt][nt], 0, 0, 0);
            }
        }
        __syncthreads();   // xs reads done before hin writes overlap
        float bl[4];
#pragma unroll
        for (int nt = 0; nt < 4; nt++) bl[nt] = bm[c0 + nt * 16 + lr];
#pragma unroll
        for (int mt = 0; mt < 4; mt++)
#pragma unroll
            for (int nt = 0; nt < 4; nt++)
#pragma unroll
                for (int r = 0; r < 4; r++) {
                    int row = mt * 16 + lq * 4 + r;
                    buf[row * S_IN + c0 + nt * 16 + lr] =
                        (row < N_) ? f2bf(acc[mt][nt][r] + bl[nt]) : (u16)0;
                }
    }
    __syncthreads();

    // ---- GAT layers ----
#pragma unroll 1
    for (int l = 0; l < LAYERS_; l++) {
        const u16* wp = wgat_t + ((size_t)l * HID_ + w64) * HID_;
        const float* a1 = ag + (size_t)l * HEADS_ * 2 * FOUT_ + wave * 128;

        // projection: h = hin @ W_head (64x512 @ 512x64)
        f32x4 acc[4][4];
#pragma unroll
        for (int mt = 0; mt < 4; mt++)
#pragma unroll
            for (int nt = 0; nt < 4; nt++) acc[mt][nt] = (f32x4){0.f, 0.f, 0.f, 0.f};
#pragma unroll 4
        for (int kt = 0; kt < 16; kt++) {
            int k0 = kt * 32;
            bf16x8 af[4];
#pragma unroll
            for (int mt = 0; mt < 4; mt++)
                af[mt] = *(const bf16x8*)&buf[(mt * 16 + lr) * S_IN + k0 + lq * 8];
#pragma unroll
            for (int nt = 0; nt < 4; nt++) {
                bf16x8 bfr = *(const bf16x8*)(wp + (size_t)(nt * 16 + lr) * HID_ + k0 + lq * 8);
#pragma unroll
                for (int mt = 0; mt < 4; mt++)
                    acc[mt][nt] = __builtin_amdgcn_mfma_f32_16x16x32_bf16(
                        af[mt], bfr, acc[mt][nt], 0, 0, 0);
            }
        }
        __syncthreads();   // (A) hin reads done -> buf becomes hT

        // transpose-store h -> hT[d][j], 8B packed (wave-local rows)
#pragma unroll
        for (int mt = 0; mt < 4; mt++)
#pragma unroll
            for (int nt = 0; nt < 4; nt++) {
                ushort4 pk;
                pk.x = f2bf(acc[mt][nt][0]); pk.y = f2bf(acc[mt][nt][1]);
                pk.z = f2bf(acc[mt][nt][2]); pk.w = f2bf(acc[mt][nt][3]);
                *(ushort4*)&buf[(w64 + nt * 16 + lr) * S_T + mt * 16 + lq * 4] = pk;
            }

        // f1/f2 (lane = node j), from own head's hT rows
        float p1 = 0.f, p2 = 0.f;
#pragma unroll 8
        for (int d = 0; d < 64; d++) {
            float hv = bf2f(buf[(w64 + d) * S_T + lane]);
            p1 = fmaf(hv, a1[d], p1);
            p2 = fmaf(hv, a1[64 + d], p2);
        }

        // column-softmax stats, SGPR broadcasts via readlane.
        // m_j = max(leaky(maskedmax_i f2[i] + f1[j]), -9e15)  (leaky monotone)
        float M = -3.0e38f;
#pragma unroll
        for (int i = 0; i < N_; i++) {
            float f2i = rdlane(p2, i);
            uint32_t bit = ((i < 32 ? cml : cmh) >> (i & 31)) & 1u;
            M = fmaxf(M, bit ? f2i : -3.0e38f);
        }
        float vm = M + p1;
        float m = fmaxf(fmaxf(vm, 0.2f * vm), -9e15f);
        float ssum = 0.f;
#pragma unroll
        for (int i = 0; i < N_; i++) {
            float f2i = rdlane(p2, i);
            float v = f2i + p1;
            v = fmaxf(v, 0.2f * v);
            uint32_t bit = ((i < 32 ? cml : cmh) >> (i & 31)) & 1u;
            float e = bit ? v : -9e15f;
            ssum += __expf(e - m);
        }
        F1[w64 + lane] = p1;
        LS[w64 + lane] = m + __logf(ssum);   // p = exp(e - LS)

        // PV: hp = P @ h, P built on the fly from LDS stat arrays
        f32x4 acc2[4][4];
#pragma unroll
        for (int mt = 0; mt < 4; mt++)
#pragma unroll
            for (int nt = 0; nt < 4; nt++) acc2[mt][nt] = (f32x4){0.f, 0.f, 0.f, 0.f};
        float f2r[4];
#pragma unroll
        for (int mt = 0; mt < 4; mt++) f2r[mt] = __shfl(p2, mt * 16 + lr, 64);
#pragma unroll
        for (int kt = 0; kt < 2; kt++) {
            int j0 = kt * 32 + lq * 8;
            f32x4 f1a = *(const f32x4*)&F1[w64 + j0];
            f32x4 f1b = *(const f32x4*)&F1[w64 + j0 + 4];
            f32x4 la  = *(const f32x4*)&LS[w64 + j0];
            f32x4 lb  = *(const f32x4*)&LS[w64 + j0 + 4];
            bf16x8 hb[4];
#pragma unroll
            for (int nt = 0; nt < 4; nt++)
                hb[nt] = *(const bf16x8*)&buf[(w64 + nt * 16 + lr) * S_T + kt * 32 + lq * 8];
#pragma unroll
            for (int mt = 0; mt < 4; mt++) {
                uint64_t mi = msk[mt * 16 + lr];
                uint32_t sh = (uint32_t)(mi >> (kt * 32)) >> (lq * 8);
                bf16x8 pf;
#pragma unroll
                for (int t = 0; t < 8; t++) {
                    float f1t = t < 4 ? f1a[t] : f1b[t - 4];
                    float lst = t < 4 ? la[t]  : lb[t - 4];
                    float v = f2r[mt] + f1t;
                    v = fmaxf(v, 0.2f * v);
                    float e = ((sh >> t) & 1u) ? v : -9e15f;
                    pf[t] = (__bf16)__expf(e - lst);
                }
#pragma unroll
                for (int nt = 0; nt < 4; nt++)
                    acc2[mt][nt] = __builtin_amdgcn_mfma_f32_16x16x32_bf16(
                        pf, hb[nt], acc2[mt][nt], 0, 0, 0);
            }
        }
        __syncthreads();   // (B) all hT/fstat reads done -> buf becomes hout

        // ELU epilogue -> hout (hin layout), pad rows zeroed
#pragma unroll
        for (int mt = 0; mt < 4; mt++)
#pragma unroll
            for (int nt = 0; nt < 4; nt++)
#pragma unroll
                for (int r = 0; r < 4; r++) {
                    float v = acc2[mt][nt][r];
                    v = v > 0.f ? v : __expf(v) - 1.f;
                    int row = mt * 16 + lq * 4 + r;
                    buf[row * S_IN + w64 + nt * 16 + lr] =
                        (row < N_) ? f2bf(v) : (u16)0;
                }
        __syncthreads();   // (C) hout complete
    }

    // ---- pool + logits + log_softmax ----
    {
        float s = 0.f;
#pragma unroll 2
        for (int n = 0; n < N_; n++) s += bf2f(buf[n * S_IN + tid]);
        fstat[tid] = s;
    }
    __syncthreads();
    if (tid < 192) {
        int c = tid >> 6, ln = tid & 63;
        float p = 0.f;
#pragma unroll
        for (int k = ln; k < HID_; k += 64) p += fstat[k] * Wout[k * 3 + c];
        for (int off = 32; off > 0; off >>= 1) p += __shfl_down(p, off, 64);
        if (ln == 0) fstat[1024 + c] = p + bout[c];
    }
    __syncthreads();
    if (tid == 0) {
        float l0 = fstat[1024], l1 = fstat[1025], l2 = fstat[1026];
        float mm = fmaxf(l0, fmaxf(l1, l2));
        float s = __expf(l0 - mm) + __expf(l1 - mm) + __expf(l2 - mm);
        float ls = mm + logf(s);
        out[b * 3 + 0] = l0 - ls;
        out[b * 3 + 1] = l1 - ls;
        out[b * 3 + 2] = l2 - ls;
    }
}

// ---------------------------------------------------------------------------
extern "C" void kernel_launch(void* const* d_in, const int* in_sizes, int n_in,
                              void* d_out, int out_size, void* d_ws, size_t ws_size,
                              hipStream_t stream)
{
    const float* x   = (const float*)d_in[0];
    const int*   adj = (const int*)d_in[1];
    const float* bng = (const float*)d_in[2];
    const float* bnb = (const float*)d_in[3];
    const float* bnm = (const float*)d_in[4];
    const float* bnv = (const float*)d_in[5];
    const float* Wm  = (const float*)d_in[6];
    const float* bm  = (const float*)d_in[7];
    const float* Wg  = (const float*)d_in[8];
    const float* ag  = (const float*)d_in[9];
    const float* Wo  = (const float*)d_in[10];
    const float* bo  = (const float*)d_in[11];
    float* out = (float*)d_out;

    // ws layout: masks | masksT | wmlp_t | wgat_t   (~3.7 MB)
    uint64_t* masks  = (uint64_t*)d_ws;
    uint64_t* masksT = masks + (size_t)B_ * 64;
    u16* wmlp_t = (u16*)(masksT + (size_t)B_ * 64);
    u16* wgat_t = wmlp_t + (size_t)HID_ * FIN_;

    int rep_total = HID_ * FIN_ + LAYERS_ * HID_ * HID_;
    repack_w<<<(rep_total + 255) / 256, 256, 0, stream>>>(Wm, Wg, wmlp_t, wgat_t);
    build_masks<<<B_, 256, 0, stream>>>(adj, masks, masksT);

    gat_fused<<<B_, 512, 0, stream>>>(
        x, bng, bnb, bnm, bnv, wmlp_t, bm, wgat_t, ag,
        masks, masksT, Wo, bo, out);
}